// Round 2
// 7265.205 us; speedup vs baseline: 3.8498x; 3.8498x over previous
//
#include <hip/hip_runtime.h>
#include <stdint.h>

// ---------------------------------------------------------------------------
// Tanh RNN on MI355X.
//   Phase 1: xproj_kernel — xp[t,b,:] = x[t,b,:] @ Wx^T + bx  (bf16 MFMA GEMM,
//            fp32 out written into the h_all region of d_out).  UNCHANGED.
//   Phase 2: rnn_scan — persistent kernel, 256 WGs (1/CU), device-wide
//            barrier per timestep, zero cache-maintenance ops:
//     * Wh register-resident: each wave owns a 16-hidden-col slice as 32
//       bf16 B-fragments (128 VGPRs), converted fp32->bf16 once.
//     * No LDS. h A-fragments load global->register with sc0 sc1 (coherent,
//       bypass stale L1/L2) under counted vmcnt pipelining.
//     * h_next written via 32-bit relaxed agent atomicExch (executes at the
//       MALL; vmcnt ack == commit). NO __threadfence anywhere: per-wave agent
//       fences lower to buffer_wbl2/buffer_inv whole-L2 walks (~2500/step in
//       the 26 ms version — that WAS the 51 us/step).
//     * Ordering: vmcnt(0) drain (atomics acked at coherence point) ->
//       relaxed agent counter add; consumers spin on counter (agent atomic
//       load = sc1 = observes MALL), then sc0 sc1 loads read committed data.
//     * HARDENED vs round 1: the spin is bounded (64K sleeps ~ 1.7 ms/step
//       worst case, never reached in normal operation) so a sync bug can
//       never hang the GPU/container — it would surface as absmax instead.
// ---------------------------------------------------------------------------

typedef __attribute__((ext_vector_type(8))) short short8;   // 8 bf16 (4 VGPRs)
typedef __attribute__((ext_vector_type(4))) float floatx4;  // MFMA accumulator

#define HID    1024
#define BATCH  256
#define TSTEPS 512
#define NWG    256   // persistent workgroups in the scan (1 per CU)

__device__ __forceinline__ unsigned short f2bf(float f) {
  union { float f; unsigned u; } v; v.f = f;
  unsigned u = v.u;
  unsigned r = u + 0x7fffu + ((u >> 16) & 1u);  // round-to-nearest-even
  return (unsigned short)(r >> 16);
}

// ---------------------------------------------------------------------------
// Phase 1: xp = x @ Wx^T + bx.  M=131072 (t*256+b), N=1024, K=1024.
// ---------------------------------------------------------------------------
__global__ __launch_bounds__(256) void xproj_kernel(
    const float* __restrict__ x, const float* __restrict__ Wx,
    const float* __restrict__ bx, float* __restrict__ xp) {
  constexpr int LDK = 40;  // 32 + 8 bf16 pad -> 80 B rows, 2-way banks (free)
  __shared__ unsigned short As[128 * LDK];
  __shared__ unsigned short Bs[128 * LDK];
  const int tid  = threadIdx.x;
  const int lane = tid & 63;
  const int wave = tid >> 6;
  const int wm = wave & 1, wn = wave >> 1;
  const int q = lane >> 4, cl = lane & 15;
  const size_t m0 = (size_t)(blockIdx.x & 1023) * 128;  // 1024 m-tiles
  const int    n0 = (int)(blockIdx.x >> 10) * 128;      // 8 n-tiles

  floatx4 acc[4][4];
#pragma unroll
  for (int i = 0; i < 4; i++)
#pragma unroll
    for (int j = 0; j < 4; j++) acc[i][j] = floatx4{0.f, 0.f, 0.f, 0.f};

  for (int k0 = 0; k0 < HID; k0 += 32) {
#pragma unroll
    for (int it = 0; it < 4; it++) {
      int f = it * 256 + tid;
      int row = f >> 3, c4 = f & 7;
      float4 va = *(const float4*)(x  + (m0 + row) * HID + k0 + c4 * 4);
      float4 vb = *(const float4*)(Wx + (size_t)(n0 + row) * HID + k0 + c4 * 4);
      uint2 pa, pb;
      pa.x = f2bf(va.x) | ((unsigned)f2bf(va.y) << 16);
      pa.y = f2bf(va.z) | ((unsigned)f2bf(va.w) << 16);
      pb.x = f2bf(vb.x) | ((unsigned)f2bf(vb.y) << 16);
      pb.y = f2bf(vb.z) | ((unsigned)f2bf(vb.w) << 16);
      *(uint2*)&As[row * LDK + c4 * 4] = pa;
      *(uint2*)&Bs[row * LDK + c4 * 4] = pb;
    }
    __syncthreads();
    short8 af[4], bfr[4];
#pragma unroll
    for (int i = 0; i < 4; i++)
      af[i] = *(const short8*)&As[(wm * 64 + i * 16 + cl) * LDK + q * 8];
#pragma unroll
    for (int j = 0; j < 4; j++)
      bfr[j] = *(const short8*)&Bs[(wn * 64 + j * 16 + cl) * LDK + q * 8];
#pragma unroll
    for (int i = 0; i < 4; i++)
#pragma unroll
      for (int j = 0; j < 4; j++)
        acc[i][j] = __builtin_amdgcn_mfma_f32_16x16x32_bf16(af[i], bfr[j],
                                                            acc[i][j], 0, 0, 0);
    __syncthreads();
  }
#pragma unroll
  for (int j = 0; j < 4; j++) {
    int col = n0 + wn * 64 + j * 16 + cl;
    float bxv = bx[col];
#pragma unroll
    for (int i = 0; i < 4; i++) {
      size_t row = m0 + wm * 64 + i * 16 + q * 4;
#pragma unroll
      for (int r = 0; r < 4; r++)
        xp[(row + r) * HID + col] = acc[i][j][r] + bxv;
    }
  }
}

// ---------------------------------------------------------------------------
// Phase 2 helpers: coherent (sc0 sc1) 16B loads with literal offsets, plain
// asm 4B loads (so our counted vmcnt bookkeeping owns ALL in-flight vmem),
// counted waits fenced with sched_barrier(0) (compiler otherwise hoists
// register-only MFMA past asm waitcnt — guide rule #18).
// ---------------------------------------------------------------------------
#define ALOAD(d, p, OFF)                                                  \
  asm volatile("global_load_dwordx4 %0, %1, off offset:" OFF " sc0 sc1"   \
               : "=v"(d) : "v"(p) : "memory")
#define FLOAD(d, p)                                                       \
  asm volatile("global_load_dword %0, %1, off" : "=v"(d) : "v"(p) : "memory")
#define VWAIT(N)                                                          \
  do {                                                                    \
    asm volatile("s_waitcnt vmcnt(" #N ")" ::: "memory");                 \
    __builtin_amdgcn_sched_barrier(0);                                    \
  } while (0)
#define MFMA8(B0)                                                         \
  _Pragma("unroll")                                                       \
  for (int k = (B0); k < (B0) + 8; k++)                                   \
    ac[k & 3] = __builtin_amdgcn_mfma_f32_16x16x32_bf16(af[k], bfr[k],    \
                                                        ac[k & 3], 0, 0, 0)

// ---------------------------------------------------------------------------
// Phase 2: persistent scan. 256 WGs x 256 threads; wave gw = bid*4+wave owns
// output tile [btile*16..+15] x [htile*16..+15] (btile = gw>>6, htile = gw&63).
// Per step per wave: 32 coherent A-loads (h rows, 64B apart) + 4 xp loads,
// 32 MFMAs in 4 pipelined groups, tanh epilogue, paired-lane atomicExch of
// bf16 h into the ping-pong buffer, then 256-arrival device barrier.
// ---------------------------------------------------------------------------
__global__ __launch_bounds__(256, 1) void rnn_scan(
    const float* __restrict__ Wh, const float* __restrict__ bh,
    float* __restrict__ out, unsigned short* __restrict__ hb0,
    unsigned short* __restrict__ hb1, int* __restrict__ ctr) {
  const int tid  = threadIdx.x;
  const int lane = tid & 63, wave = tid >> 6;
  const int q = lane >> 4, cl = lane & 15;
  const int gw    = (int)blockIdx.x * 4 + wave;  // 0..1023
  const int btile = gw >> 6;                     // 0..15  (16 batch rows)
  const int htile = gw & 63;                     // 0..63  (16 hidden cols)
  const int gcol  = htile * 16 + cl;             // this lane's hidden column
  const int grow0 = btile * 16 + q * 4;          // first output row (C layout)

  // ---- one-time: Wh rows [gcol] -> 32 bf16 B-fragments in registers ------
  short8 bfr[32];
  {
    const float* wp = Wh + (size_t)gcol * HID + q * 8;
#pragma unroll
    for (int kb = 0; kb < 32; kb++) {
      float4 lo = *(const float4*)(wp + kb * 32);
      float4 hi = *(const float4*)(wp + kb * 32 + 4);
      short8 b;
      b[0] = (short)f2bf(lo.x); b[1] = (short)f2bf(lo.y);
      b[2] = (short)f2bf(lo.z); b[3] = (short)f2bf(lo.w);
      b[4] = (short)f2bf(hi.x); b[5] = (short)f2bf(hi.y);
      b[6] = (short)f2bf(hi.z); b[7] = (short)f2bf(hi.w);
      bfr[kb] = b;
    }
  }
  const float bhv  = bh[gcol];
  float* const hall = out + (size_t)BATCH * HID;  // h_all region of d_out

  for (int t = 0; t < TSTEPS; t++) {
    const unsigned short* __restrict__ hcur = (t & 1) ? hb1 : hb0;
    unsigned short* __restrict__       hnxt = (t & 1) ? hb0 : hb1;
    // A-fragment base: lane cl -> h row btile*16+cl, k-offset q*8 (bf16)
    const unsigned short* ap = hcur + (size_t)(btile * 16 + cl) * HID + q * 8;
    float* xp0 = hall + ((size_t)t * BATCH + grow0) * HID + gcol;

    short8 af[32];
    // groups 0+1 (16 loads) then xp (4 loads): 20 outstanding
    ALOAD(af[0],  ap, "0");    ALOAD(af[1],  ap, "64");
    ALOAD(af[2],  ap, "128");  ALOAD(af[3],  ap, "192");
    ALOAD(af[4],  ap, "256");  ALOAD(af[5],  ap, "320");
    ALOAD(af[6],  ap, "384");  ALOAD(af[7],  ap, "448");
    ALOAD(af[8],  ap, "512");  ALOAD(af[9],  ap, "576");
    ALOAD(af[10], ap, "640");  ALOAD(af[11], ap, "704");
    ALOAD(af[12], ap, "768");  ALOAD(af[13], ap, "832");
    ALOAD(af[14], ap, "896");  ALOAD(af[15], ap, "960");
    float xv[4];
    FLOAD(xv[0], xp0);
    FLOAD(xv[1], xp0 + HID);
    FLOAD(xv[2], xp0 + 2 * HID);
    FLOAD(xv[3], xp0 + 3 * HID);

    floatx4 ac[4];
#pragma unroll
    for (int j = 0; j < 4; j++) ac[j] = floatx4{0.f, 0.f, 0.f, 0.f};

    VWAIT(12);  // g0 done (g1+xv in flight)
    MFMA8(0);
    ALOAD(af[16], ap, "1024"); ALOAD(af[17], ap, "1088");
    ALOAD(af[18], ap, "1152"); ALOAD(af[19], ap, "1216");
    ALOAD(af[20], ap, "1280"); ALOAD(af[21], ap, "1344");
    ALOAD(af[22], ap, "1408"); ALOAD(af[23], ap, "1472");
    VWAIT(12);  // g1 done (xv+g2 in flight)
    MFMA8(8);
    ALOAD(af[24], ap, "1536"); ALOAD(af[25], ap, "1600");
    ALOAD(af[26], ap, "1664"); ALOAD(af[27], ap, "1728");
    ALOAD(af[28], ap, "1792"); ALOAD(af[29], ap, "1856");
    ALOAD(af[30], ap, "1920"); ALOAD(af[31], ap, "1984");
    VWAIT(8);   // xv + g2 done (g3 in flight)
    MFMA8(16);
    VWAIT(0);   // g3 done
    MFMA8(24);

    floatx4 accs = (ac[0] + ac[1]) + (ac[2] + ac[3]);  // same chain merge order

    // epilogue: h = tanh(z + xp + bh); h_all fp32 (same-thread overwrite of
    // xp, plain cached stores), final-step h_final, bf16 h via atomicExch.
    float hv[4]; unsigned hu[4];
#pragma unroll
    for (int r = 0; r < 4; r++) {
      float z = accs[r] + xv[r] + bhv;
      float h = tanhf(z);
      xp0[r * HID] = h;
      hv[r] = h;
      hu[r] = f2bf(h);
    }
    if (t == TSTEPS - 1) {
#pragma unroll
      for (int r = 0; r < 4; r++)
        out[(size_t)(grow0 + r) * HID + gcol] = hv[r];
    }
    // pair even/odd lanes (cols gcol, gcol+1) -> one u32 atomic swap at MALL
#pragma unroll
    for (int r = 0; r < 4; r++) {
      unsigned other = (unsigned)__shfl_xor((int)hu[r], 1);
      if (!(cl & 1)) {
        unsigned pk = (hu[r] & 0xffffu) | (other << 16);
        unsigned* dst = (unsigned*)(hnxt + (size_t)(grow0 + r) * HID + gcol);
        (void)__hip_atomic_exchange(dst, pk, __ATOMIC_RELAXED,
                                    __HIP_MEMORY_SCOPE_AGENT);
      }
    }

    // device barrier, zero cache-maintenance: drain (atomics acked at the
    // coherence point), WG-local sync, one relaxed agent add + BOUNDED spin
    // per WG (cap never reached normally; makes a sync bug un-hangable).
    asm volatile("s_waitcnt vmcnt(0)" ::: "memory");
    __syncthreads();
    if (tid == 0) {
      __hip_atomic_fetch_add(&ctr[t], 1, __ATOMIC_RELAXED,
                             __HIP_MEMORY_SCOPE_AGENT);
      int guard = 0;
      while (__hip_atomic_load(&ctr[t], __ATOMIC_RELAXED,
                               __HIP_MEMORY_SCOPE_AGENT) < NWG &&
             guard < (1 << 16)) {
        __builtin_amdgcn_s_sleep(1);
        ++guard;
      }
    }
    __syncthreads();
  }
}

// ---------------------------------------------------------------------------
extern "C" void kernel_launch(void* const* d_in, const int* in_sizes, int n_in,
                              void* d_out, int out_size, void* d_ws, size_t ws_size,
                              hipStream_t stream) {
  const float* x  = (const float*)d_in[0];
  const float* Wx = (const float*)d_in[1];
  const float* bx = (const float*)d_in[2];
  const float* Wh = (const float*)d_in[3];
  const float* bh = (const float*)d_in[4];
  float* out = (float*)d_out;

  // d_ws layout: [0,2048) step counters | 4096: hb0 (512 KB) | hb1 (512 KB)
  int* ctr = (int*)d_ws;
  unsigned short* hb0 = (unsigned short*)((char*)d_ws + 4096);
  unsigned short* hb1 = (unsigned short*)((char*)d_ws + 4096 + 524288);

  hipMemsetAsync(d_ws, 0, 4096 + 2 * 524288, stream);  // zero ctr + h0 = 0

  // Phase 1: xp -> h_all region of d_out (fp32)
  xproj_kernel<<<dim3(8192), dim3(256), 0, stream>>>(
      x, Wx, bx, out + (size_t)BATCH * HID);

  // Phase 2: persistent barriered scan (no LDS, Wh in registers)
  rnn_scan<<<dim3(NWG), dim3(256), 0, stream>>>(Wh, bh, out, hb0, hb1, ctr);
}